// Round 8
// baseline (639.933 us; speedup 1.0000x reference)
//
#include <hip/hip_runtime.h>
#include <hip/hip_bf16.h>

typedef __bf16 bf16x8 __attribute__((ext_vector_type(8)));
typedef float  f32x4  __attribute__((ext_vector_type(4)));

#define GAS __attribute__((address_space(1)))
#define LAS __attribute__((address_space(3)))

__device__ __forceinline__ unsigned short f2bf(float f) {
    __hip_bfloat16 h = __float2bfloat16(f);
    return *reinterpret_cast<unsigned short*>(&h);
}
__device__ __forceinline__ float bf2f(unsigned short u) {
    __hip_bfloat16 h;
    *reinterpret_cast<unsigned short*>(&h) = u;
    return __bfloat162float(h);
}
__device__ __forceinline__ void storeval(float* p, float v) { *p = v; }
__device__ __forceinline__ void storeval(unsigned short* p, float v) { *p = f2bf(v); }

// ---------------------------------------------------------------------------
// prep: f32 -> bf16 bulk convert (vectorized)
// ---------------------------------------------------------------------------
__global__ void prep_x_kernel(const float* __restrict__ in, unsigned short* __restrict__ out, int total) {
    int idx = (blockIdx.x * 256 + threadIdx.x) * 4;
    if (idx >= total) return;
    float4 v = *reinterpret_cast<const float4*>(in + idx);
    ushort4 o;
    o.x = f2bf(v.x); o.y = f2bf(v.y); o.z = f2bf(v.z); o.w = f2bf(v.w);
    *reinterpret_cast<ushort4*>(out + idx) = o;
}

// ---------------------------------------------------------------------------
// prep: W[k][ci][co] f32 -> Wp[k][h][co][c8*8+j] bf16 (BK=64 halves,
// XOR-swizzled at 16B-chunk granularity — round-3-verified layout)
// ---------------------------------------------------------------------------
__global__ void prep_w_kernel(const float* __restrict__ W, unsigned short* __restrict__ Wp) {
    int idx = blockIdx.x * 256 + threadIdx.x;   // < 27*16384
    int k  = idx >> 14;
    int r  = idx & 16383;
    int h  = r >> 13;
    int rr = r & 8191;
    int co = rr >> 6;
    int cc = rr & 63;
    int c8 = cc >> 3, j = cc & 7;
    int ci = (h << 6) | ((c8 ^ (co & 7)) << 3) | j;
    Wp[idx] = f2bf(W[(k << 14) + ci * 128 + co]);
}

// ---------------------------------------------------------------------------
// FiLM: e[b][j] = emb[b] . Wt[:,j] + bt[j]. One wave per output element.
// ---------------------------------------------------------------------------
__global__ void film_kernel(const float* __restrict__ emb, const float* __restrict__ Wt,
                            const float* __restrict__ bt, float* __restrict__ e) {
    int gw = blockIdx.x * 4 + (threadIdx.x >> 6);   // 0..2047
    int lane = threadIdx.x & 63;
    int b = gw >> 8, j = gw & 255;
    float a = 0.f;
    for (int i = lane; i < 512; i += 64) a += emb[b * 512 + i] * Wt[i * 256 + j];
#pragma unroll
    for (int off = 32; off; off >>= 1) a += __shfl_xor(a, off);
    if (lane == 0) e[gw] = a + bt[j];
}

// ---------------------------------------------------------------------------
// Gather-GEMM sparse conv. BM=128, BK=64, SINGLE-buffered LDS (34.8 KB/block
// -> 4 blocks/CU, 16 waves: TLP hides the gather latency instead of a deeper
// pipeline — rounds 3/7 showed depth-1 prefetch is neutral and fewer blocks
// hurt). nbr indices live in VGPRs (double-buffered across k, prefetched one
// k ahead) — no nbrS in LDS. Fused instance-norm stats epilogue.
// ---------------------------------------------------------------------------
template <typename OUT_T>
__global__ __launch_bounds__(256, 4) void conv_kernel(
        const unsigned short* __restrict__ X,    // [N][128] bf16
        const int* __restrict__ nbr,             // [N][27]
        const unsigned short* __restrict__ Wp,   // [27][2][128][64] bf16 pre-swizzled
        OUT_T* __restrict__ out,
        const int* __restrict__ bidx,
        float* __restrict__ gsum, float* __restrict__ gsq, float* __restrict__ gcnt,
        int N) {
    __shared__ __align__(16) unsigned short As[128 * 64];
    __shared__ __align__(16) unsigned short Bs[128 * 64];
    __shared__ float ssum[2][128];
    __shared__ float ssq[2][128];
    __shared__ float shi;

    const int t = threadIdx.x;
    const int lane = t & 63;
    const int wave = t >> 6;
    const int n0 = blockIdx.x * 128;
    const int l15 = lane & 15, l4 = lane >> 4;
    const int wr = wave >> 1, wc = wave & 1;
    const int nrow = t >> 3;                 // row group this thread stages (4 rows: +32i)
    const int c8f = t & 7;                   // staging chunk-in-row

    if (t < 128) { ssum[0][t] = 0.f; ssum[1][t] = 0.f; ssq[0][t] = 0.f; ssq[1][t] = 0.f; }
    if (t == 0) shi = 0.f;

    f32x4 acc[4][4];
#pragma unroll
    for (int mi = 0; mi < 4; mi++)
#pragma unroll
        for (int ni = 0; ni < 4; ni++) acc[mi][ni] = (f32x4){0.f, 0.f, 0.f, 0.f};

    // nbr prefetch registers: rn = column k, rn2 = column k+1 (in flight)
    int rn[4], rn2[4];
#pragma unroll
    for (int i = 0; i < 4; i++) rn[i] = nbr[(size_t)(n0 + nrow + 32 * i) * 27 + 0];

    auto stageA = [&](int h) {
#pragma unroll
        for (int i = 0; i < 4; ++i) {
            int row = 32 * i + nrow;
            int g = c8f ^ (row & 7);          // inverse-swizzled source chunk
            __builtin_amdgcn_global_load_lds(
                (const GAS void*)(X + (size_t)rn[i] * 128 + h * 64 + g * 8),
                (LAS void*)(&As[(size_t)(i * 256 + wave * 64) * 8]), 16, 0, 0);
        }
    };
    auto stageB = [&](int sidx) {
        const unsigned short* wsrc = Wp + (size_t)sidx * 8192;
#pragma unroll
        for (int i = 0; i < 4; ++i) {
            __builtin_amdgcn_global_load_lds(
                (const GAS void*)(wsrc + (size_t)(i * 256 + t) * 8),
                (LAS void*)(&Bs[(size_t)(i * 256 + wave * 64) * 8]), 16, 0, 0);
        }
    };
    auto compute = [&]() {
#pragma unroll
        for (int kk = 0; kk < 2; ++kk) {
            const int c8 = kk * 4 + l4;
            bf16x8 a[4], b[4];
#pragma unroll
            for (int mi = 0; mi < 4; mi++) {
                int row = wr * 64 + mi * 16 + l15;
                a[mi] = *reinterpret_cast<const bf16x8*>(&As[row * 64 + (c8 ^ (row & 7)) * 8]);
            }
#pragma unroll
            for (int ni = 0; ni < 4; ni++) {
                int co = wc * 64 + ni * 16 + l15;
                b[ni] = *reinterpret_cast<const bf16x8*>(&Bs[co * 64 + (c8 ^ (co & 7)) * 8]);
            }
#pragma unroll
            for (int mi = 0; mi < 4; mi++)
#pragma unroll
                for (int ni = 0; ni < 4; ni++)
                    acc[mi][ni] = __builtin_amdgcn_mfma_f32_16x16x32_bf16(a[mi], b[ni], acc[mi][ni], 0, 0, 0);
        }
    };

    __syncthreads();   // stats-LDS init visible

    for (int k = 0; k < 27; ++k) {
        // ---- h = 0 ----
        stageA(0);
        stageB(2 * k);
        {
            int kn = k < 26 ? k + 1 : 26;     // avoid OOB on last k (values unused)
#pragma unroll
            for (int i = 0; i < 4; i++) rn2[i] = nbr[(size_t)(n0 + nrow + 32 * i) * 27 + kn];
        }
        __syncthreads();   // loads landed
        compute();
        __syncthreads();   // all reads done before overwrite
        // ---- h = 1 ----
        stageA(1);
        stageB(2 * k + 1);
        __syncthreads();
        compute();
        __syncthreads();
#pragma unroll
        for (int i = 0; i < 4; i++) rn[i] = rn2[i];
    }

    // ---- epilogue: store + fused instance-norm stats (round-3-verified) ----
    const int b_lo = bidx[n0];
    const int b_hi = bidx[n0 + 127];
    const bool split = (b_hi != b_lo);

    float ps0[4] = {0.f, 0.f, 0.f, 0.f}, ps1[4] = {0.f, 0.f, 0.f, 0.f};
    float pq0[4] = {0.f, 0.f, 0.f, 0.f}, pq1[4] = {0.f, 0.f, 0.f, 0.f};
#pragma unroll
    for (int mi = 0; mi < 4; mi++) {
#pragma unroll
        for (int j = 0; j < 4; j++) {
            int rowm = wr * 64 + mi * 16 + l4 * 4 + j;
            bool hi = split && (bidx[n0 + rowm] != b_lo);
#pragma unroll
            for (int ni = 0; ni < 4; ni++) {
                float v = acc[mi][ni][j];
                float v1 = hi ? v : 0.f;
                float v0 = v - v1;
                ps0[ni] += v0; pq0[ni] += v0 * v;
                ps1[ni] += v1; pq1[ni] += v1 * v;
                int col = wc * 64 + ni * 16 + l15;
                storeval(out + (size_t)(n0 + rowm) * 128 + col, v);
            }
        }
    }
#pragma unroll
    for (int ni = 0; ni < 4; ni++) {
        int col = wc * 64 + ni * 16 + l15;
        atomicAdd(&ssum[0][col], ps0[ni]);
        atomicAdd(&ssq[0][col], pq0[ni]);
        if (split) {
            atomicAdd(&ssum[1][col], ps1[ni]);
            atomicAdd(&ssq[1][col], pq1[ni]);
        }
    }
    if (split && wave < 2) {
        bool hi2 = (bidx[n0 + t] != b_lo);
        unsigned long long m = __ballot(hi2);
        if (lane == 0) atomicAdd(&shi, (float)__popcll(m));
    }
    __syncthreads();
    {
        int slot = t >> 7, c = t & 127;
        if (slot == 0 || split) {
            int b = slot ? b_hi : b_lo;
            atomicAdd(&gsum[b * 128 + c], ssum[slot][c]);
            atomicAdd(&gsq[b * 128 + c], ssq[slot][c]);
        }
        if (t == 0) {
            float nhi = shi;
            atomicAdd(&gcnt[b_lo], 128.f - nhi);
            if (split) atomicAdd(&gcnt[b_hi], nhi);
        }
    }
}

// ---------------------------------------------------------------------------
// apply1: y = elu( norm(out1) * (1+scale) + shift )  -> bf16
// ---------------------------------------------------------------------------
__global__ void apply1_kernel(const unsigned short* __restrict__ o1, const int* __restrict__ bidx,
                              const float* __restrict__ gsum, const float* __restrict__ gsq,
                              const float* __restrict__ gcnt, const float* __restrict__ e,
                              unsigned short* __restrict__ y, int N) {
    int idx = blockIdx.x * 256 + threadIdx.x;
    int n = idx >> 5;
    if (n >= N) return;
    int c0 = (idx & 31) << 2;
    int b = bidx[n];
    float icnt = 1.0f / fmaxf(gcnt[b], 1.0f);
    ushort4 vv = *reinterpret_cast<const ushort4*>(o1 + (size_t)n * 128 + c0);
    const unsigned short* pv = reinterpret_cast<const unsigned short*>(&vv);
    unsigned short res[4];
#pragma unroll
    for (int j = 0; j < 4; j++) {
        int c = c0 + j;
        float m = gsum[b * 128 + c] * icnt;
        float var = gsq[b * 128 + c] * icnt - m * m;
        float rs = rsqrtf(fmaxf(var, 0.f) + 1e-6f);
        float xn = (bf2f(pv[j]) - m) * rs;
        float sc = e[b * 256 + c];
        float sh = e[b * 256 + 128 + c];
        float tt = xn * (1.0f + sc) + sh;
        float r = tt > 0.f ? tt : expm1f(tt);
        res[j] = f2bf(r);
    }
    *reinterpret_cast<ushort4*>(y + (size_t)n * 128 + c0) = *reinterpret_cast<ushort4*>(res);
}

// ---------------------------------------------------------------------------
// apply2: out = elu( norm(out2) + x_feats )  -> f32, in place on d_out
// ---------------------------------------------------------------------------
__global__ void apply2_kernel(float* __restrict__ o2, const float* __restrict__ xf,
                              const int* __restrict__ bidx, const float* __restrict__ gsum,
                              const float* __restrict__ gsq, const float* __restrict__ gcnt, int N) {
    int idx = blockIdx.x * 256 + threadIdx.x;
    int n = idx >> 5;
    if (n >= N) return;
    int c0 = (idx & 31) << 2;
    int b = bidx[n];
    float icnt = 1.0f / fmaxf(gcnt[b], 1.0f);
    float4 v = *reinterpret_cast<const float4*>(o2 + (size_t)n * 128 + c0);
    float4 xv = *reinterpret_cast<const float4*>(xf + (size_t)n * 128 + c0);
    const float* pv = reinterpret_cast<const float*>(&v);
    const float* px = reinterpret_cast<const float*>(&xv);
    float res[4];
#pragma unroll
    for (int j = 0; j < 4; j++) {
        int c = c0 + j;
        float m = gsum[b * 128 + c] * icnt;
        float var = gsq[b * 128 + c] * icnt - m * m;
        float rs = rsqrtf(fmaxf(var, 0.f) + 1e-6f);
        float zn = (pv[j] - m) * rs;
        float r2 = zn + px[j];
        res[j] = r2 > 0.f ? r2 : expm1f(r2);
    }
    *reinterpret_cast<float4*>(o2 + (size_t)n * 128 + c0) =
        *reinterpret_cast<float4*>(res);
}

// ---------------------------------------------------------------------------
extern "C" void kernel_launch(void* const* d_in, const int* in_sizes, int n_in,
                              void* d_out, int out_size, void* d_ws, size_t ws_size,
                              hipStream_t stream) {
    const float* x    = (const float*)d_in[0];
    const float* emb  = (const float*)d_in[1];
    const float* W1   = (const float*)d_in[2];
    const float* W2   = (const float*)d_in[3];
    const float* Wt   = (const float*)d_in[4];
    const float* bt   = (const float*)d_in[5];
    const int* bidx   = (const int*)d_in[6];
    const int* nbr    = (const int*)d_in[7];
    float* out        = (float*)d_out;
    const int N = in_sizes[0] / 128;

    char* ws = (char*)d_ws;
    unsigned short* xb  = (unsigned short*)ws;                          // N*128 bf16 (reused as y)
    unsigned short* o1b = (unsigned short*)(ws + (size_t)N * 256);      // N*128 bf16
    unsigned short* w1p = (unsigned short*)(ws + (size_t)N * 512);      // 27*16384 bf16
    unsigned short* w2p = w1p + 27 * 16384;
    float* e    = (float*)(w2p + 27 * 16384);                           // 8*256
    float* st   = e + 2048;
    float* sum1 = st;
    float* sq1  = st + 1024;
    float* cnt1 = st + 2048;
    float* sum2 = st + 2056;
    float* sq2  = st + 3080;
    float* cnt2 = st + 4104;

    hipMemsetAsync(st, 0, 4112 * sizeof(float), stream);

    int total = N * 128;
    prep_x_kernel<<<(total / 4 + 255) / 256, 256, 0, stream>>>(x, xb, total);
    prep_w_kernel<<<27 * 64, 256, 0, stream>>>(W1, w1p);
    prep_w_kernel<<<27 * 64, 256, 0, stream>>>(W2, w2p);
    film_kernel<<<512, 256, 0, stream>>>(emb, Wt, bt, e);

    conv_kernel<unsigned short><<<N / 128, 256, 0, stream>>>(xb, nbr, w1p, o1b, bidx, sum1, sq1, cnt1, N);
    apply1_kernel<<<(N * 32 + 255) / 256, 256, 0, stream>>>(o1b, bidx, sum1, sq1, cnt1, e, xb, N);

    conv_kernel<float><<<N / 128, 256, 0, stream>>>(xb, nbr, w2p, out, bidx, sum2, sq2, cnt2, N);
    apply2_kernel<<<(N * 32 + 255) / 256, 256, 0, stream>>>(out, x, bidx, sum2, sq2, cnt2, N);
}

// Round 11
// 443.213 us; speedup vs baseline: 1.4438x; 1.4438x over previous
//
#include <hip/hip_runtime.h>
#include <hip/hip_bf16.h>

typedef __bf16 bf16x8 __attribute__((ext_vector_type(8)));
typedef float  f32x4  __attribute__((ext_vector_type(4)));

#define GAS __attribute__((address_space(1)))
#define LAS __attribute__((address_space(3)))

__device__ __forceinline__ unsigned short f2bf(float f) {
    __hip_bfloat16 h = __float2bfloat16(f);
    return *reinterpret_cast<unsigned short*>(&h);
}
__device__ __forceinline__ float bf2f(unsigned short u) {
    __hip_bfloat16 h;
    *reinterpret_cast<unsigned short*>(&h) = u;
    return __bfloat162float(h);
}
__device__ __forceinline__ void storeval(float* p, float v) { *p = v; }
__device__ __forceinline__ void storeval(unsigned short* p, float v) { *p = f2bf(v); }

// ---------------------------------------------------------------------------
// prep: f32 -> bf16 bulk convert (vectorized)
// ---------------------------------------------------------------------------
__global__ void prep_x_kernel(const float* __restrict__ in, unsigned short* __restrict__ out, int total) {
    int idx = (blockIdx.x * 256 + threadIdx.x) * 4;
    if (idx >= total) return;
    float4 v = *reinterpret_cast<const float4*>(in + idx);
    ushort4 o;
    o.x = f2bf(v.x); o.y = f2bf(v.y); o.z = f2bf(v.z); o.w = f2bf(v.w);
    *reinterpret_cast<ushort4*>(out + idx) = o;
}

// ---------------------------------------------------------------------------
// prep: W[k][ci][co] f32 -> Wp[k][h][co][c8*8+j] bf16 (BK=64 halves,
// XOR-swizzled at 16B-chunk granularity — round-3-verified layout)
// ---------------------------------------------------------------------------
__global__ void prep_w_kernel(const float* __restrict__ W, unsigned short* __restrict__ Wp) {
    int idx = blockIdx.x * 256 + threadIdx.x;   // < 27*16384
    int k  = idx >> 14;
    int r  = idx & 16383;
    int h  = r >> 13;
    int rr = r & 8191;
    int co = rr >> 6;
    int cc = rr & 63;
    int c8 = cc >> 3, j = cc & 7;
    int ci = (h << 6) | ((c8 ^ (co & 7)) << 3) | j;
    Wp[idx] = f2bf(W[(k << 14) + ci * 128 + co]);
}

// ---------------------------------------------------------------------------
// FiLM: e[b][j] = emb[b] . Wt[:,j] + bt[j]. One wave per output element.
// ---------------------------------------------------------------------------
__global__ void film_kernel(const float* __restrict__ emb, const float* __restrict__ Wt,
                            const float* __restrict__ bt, float* __restrict__ e) {
    int gw = blockIdx.x * 4 + (threadIdx.x >> 6);   // 0..2047
    int lane = threadIdx.x & 63;
    int b = gw >> 8, j = gw & 255;
    float a = 0.f;
    for (int i = lane; i < 512; i += 64) a += emb[b * 512 + i] * Wt[i * 256 + j];
#pragma unroll
    for (int off = 32; off; off >>= 1) a += __shfl_xor(a, off);
    if (lane == 0) e[gw] = a + bt[j];
}

// ---------------------------------------------------------------------------
// Gather-GEMM sparse conv, 2-phase pipelined, H-MAJOR step order:
//   sidx = h*27 + k  (all 27 offsets over X[:,0:64] first, then X[:,64:128]).
//   Halves the active gather footprint per phase (33 -> 16.5 MB) to raise
//   the per-XCD L2 hit rate on the random gather (round-3 kernel otherwise
//   unchanged: 128x128 tile, BK=64, double-buffered LDS, fused stats).
// ---------------------------------------------------------------------------
template <typename OUT_T>
__global__ __launch_bounds__(256, 2) void conv_kernel(
        const unsigned short* __restrict__ X,    // [N][128] bf16
        const int* __restrict__ nbr,             // [N][27]
        const unsigned short* __restrict__ Wp,   // [27][2][128][64] bf16 pre-swizzled
        OUT_T* __restrict__ out,
        const int* __restrict__ bidx,
        float* __restrict__ gsum, float* __restrict__ gsq, float* __restrict__ gcnt,
        int N) {
    __shared__ __align__(16) unsigned short As[2][128 * 64];
    __shared__ __align__(16) unsigned short Bs[2][128 * 64];
    __shared__ int nbrS[128 * 27];
    __shared__ float ssum[2][128];
    __shared__ float ssq[2][128];
    __shared__ float shi;   // count of rows with b == b_hi (when split block)

    const int t = threadIdx.x;
    const int lane = t & 63;
    const int wave = t >> 6;
    const int n0 = blockIdx.x * 128;

    for (int i = t; i < 128 * 27; i += 256) nbrS[i] = nbr[(size_t)n0 * 27 + i];
    if (t < 128) { ssum[0][t] = 0.f; ssum[1][t] = 0.f; ssq[0][t] = 0.f; ssq[1][t] = 0.f; }
    if (t == 0) shi = 0.f;

    f32x4 acc[4][4];
#pragma unroll
    for (int mi = 0; mi < 4; mi++)
#pragma unroll
        for (int ni = 0; ni < 4; ni++) acc[mi][ni] = (f32x4){0.f, 0.f, 0.f, 0.f};

    const int wr = wave >> 1, wc = wave & 1;
    const int l15 = lane & 15, l4 = lane >> 4;

    // h-major: sidx 0..26 -> (h=0, k=sidx); 27..53 -> (h=1, k=sidx-27)
    auto stage = [&](int sidx) {
        const int h1 = sidx >= 27 ? 1 : 0;
        const int k1 = sidx - h1 * 27;
        unsigned short* Ad = &As[sidx & 1][0];
        unsigned short* Bd = &Bs[sidx & 1][0];
#pragma unroll
        for (int i = 0; i < 4; ++i) {
            int chunk = i * 256 + t;
            int row = chunk >> 3;
            int c8 = chunk & 7;
            int g = c8 ^ (row & 7);               // inverse-swizzled source chunk
            int srow = nbrS[row * 27 + k1];
            __builtin_amdgcn_global_load_lds(
                (const GAS void*)(X + (size_t)srow * 128 + h1 * 64 + g * 8),
                (LAS void*)(Ad + (size_t)(i * 256 + wave * 64) * 8), 16, 0, 0);
        }
        const unsigned short* wsrc = Wp + (size_t)(k1 * 2 + h1) * 8192;
#pragma unroll
        for (int i = 0; i < 4; ++i) {
            __builtin_amdgcn_global_load_lds(
                (const GAS void*)(wsrc + (size_t)(i * 256 + t) * 8),
                (LAS void*)(Bd + (size_t)(i * 256 + wave * 64) * 8), 16, 0, 0);
        }
    };

    __syncthreads();           // nbrS + stats LDS ready
    stage(0);
    __syncthreads();           // buf 0 landed (vmcnt drain)

#pragma unroll 2
    for (int s = 0; s < 54; ++s) {
        if (s < 53) stage(s + 1);          // prefetch into buf[(s+1)&1]
        const int buf = s & 1;
#pragma unroll
        for (int kk = 0; kk < 2; ++kk) {
            const int c8 = kk * 4 + l4;
            bf16x8 a[4], b[4];
#pragma unroll
            for (int mi = 0; mi < 4; mi++) {
                int row = wr * 64 + mi * 16 + l15;
                a[mi] = *reinterpret_cast<const bf16x8*>(&As[buf][row * 64 + (c8 ^ (row & 7)) * 8]);
            }
#pragma unroll
            for (int ni = 0; ni < 4; ni++) {
                int co = wc * 64 + ni * 16 + l15;
                b[ni] = *reinterpret_cast<const bf16x8*>(&Bs[buf][co * 64 + (c8 ^ (co & 7)) * 8]);
            }
#pragma unroll
            for (int mi = 0; mi < 4; mi++)
#pragma unroll
                for (int ni = 0; ni < 4; ni++)
                    acc[mi][ni] = __builtin_amdgcn_mfma_f32_16x16x32_bf16(a[mi], b[ni], acc[mi][ni], 0, 0, 0);
        }
        __syncthreads();       // drains stage(s+1) loads; orders buffer reuse
    }

    // ---- epilogue: store + fused instance-norm stats ----
    const int b_lo = bidx[n0];
    const int b_hi = bidx[n0 + 127];
    const bool split = (b_hi != b_lo);

    float ps0[4] = {0.f, 0.f, 0.f, 0.f}, ps1[4] = {0.f, 0.f, 0.f, 0.f};
    float pq0[4] = {0.f, 0.f, 0.f, 0.f}, pq1[4] = {0.f, 0.f, 0.f, 0.f};
#pragma unroll
    for (int mi = 0; mi < 4; mi++) {
#pragma unroll
        for (int j = 0; j < 4; j++) {
            int rowm = wr * 64 + mi * 16 + l4 * 4 + j;
            bool hi = split && (bidx[n0 + rowm] != b_lo);
#pragma unroll
            for (int ni = 0; ni < 4; ni++) {
                float v = acc[mi][ni][j];
                float v1 = hi ? v : 0.f;
                float v0 = v - v1;
                ps0[ni] += v0; pq0[ni] += v0 * v;
                ps1[ni] += v1; pq1[ni] += v1 * v;
                int col = wc * 64 + ni * 16 + l15;
                storeval(out + (size_t)(n0 + rowm) * 128 + col, v);
            }
        }
    }
#pragma unroll
    for (int ni = 0; ni < 4; ni++) {
        int col = wc * 64 + ni * 16 + l15;
        atomicAdd(&ssum[0][col], ps0[ni]);
        atomicAdd(&ssq[0][col], pq0[ni]);
        if (split) {
            atomicAdd(&ssum[1][col], ps1[ni]);
            atomicAdd(&ssq[1][col], pq1[ni]);
        }
    }
    if (split && wave < 2) {
        bool hi = (bidx[n0 + t] != b_lo);
        unsigned long long m = __ballot(hi);
        if (lane == 0) atomicAdd(&shi, (float)__popcll(m));
    }
    __syncthreads();
    {
        int slot = t >> 7, c = t & 127;
        if (slot == 0 || split) {
            int b = slot ? b_hi : b_lo;
            atomicAdd(&gsum[b * 128 + c], ssum[slot][c]);
            atomicAdd(&gsq[b * 128 + c], ssq[slot][c]);
        }
        if (t == 0) {
            float nhi = shi;
            atomicAdd(&gcnt[b_lo], 128.f - nhi);
            if (split) atomicAdd(&gcnt[b_hi], nhi);
        }
    }
}

// ---------------------------------------------------------------------------
// apply1: y = elu( norm(out1) * (1+scale) + shift )  -> bf16
// ---------------------------------------------------------------------------
__global__ void apply1_kernel(const unsigned short* __restrict__ o1, const int* __restrict__ bidx,
                              const float* __restrict__ gsum, const float* __restrict__ gsq,
                              const float* __restrict__ gcnt, const float* __restrict__ e,
                              unsigned short* __restrict__ y, int N) {
    int idx = blockIdx.x * 256 + threadIdx.x;
    int n = idx >> 5;
    if (n >= N) return;
    int c0 = (idx & 31) << 2;
    int b = bidx[n];
    float icnt = 1.0f / fmaxf(gcnt[b], 1.0f);
    ushort4 vv = *reinterpret_cast<const ushort4*>(o1 + (size_t)n * 128 + c0);
    const unsigned short* pv = reinterpret_cast<const unsigned short*>(&vv);
    unsigned short res[4];
#pragma unroll
    for (int j = 0; j < 4; j++) {
        int c = c0 + j;
        float m = gsum[b * 128 + c] * icnt;
        float var = gsq[b * 128 + c] * icnt - m * m;
        float rs = rsqrtf(fmaxf(var, 0.f) + 1e-6f);
        float xn = (bf2f(pv[j]) - m) * rs;
        float sc = e[b * 256 + c];
        float sh = e[b * 256 + 128 + c];
        float tt = xn * (1.0f + sc) + sh;
        float r = tt > 0.f ? tt : expm1f(tt);
        res[j] = f2bf(r);
    }
    *reinterpret_cast<ushort4*>(y + (size_t)n * 128 + c0) = *reinterpret_cast<ushort4*>(res);
}

// ---------------------------------------------------------------------------
// apply2: out = elu( norm(out2) + x_feats )  -> f32, in place on d_out
// ---------------------------------------------------------------------------
__global__ void apply2_kernel(float* __restrict__ o2, const float* __restrict__ xf,
                              const int* __restrict__ bidx, const float* __restrict__ gsum,
                              const float* __restrict__ gsq, const float* __restrict__ gcnt, int N) {
    int idx = blockIdx.x * 256 + threadIdx.x;
    int n = idx >> 5;
    if (n >= N) return;
    int c0 = (idx & 31) << 2;
    int b = bidx[n];
    float icnt = 1.0f / fmaxf(gcnt[b], 1.0f);
    float4 v = *reinterpret_cast<const float4*>(o2 + (size_t)n * 128 + c0);
    float4 xv = *reinterpret_cast<const float4*>(xf + (size_t)n * 128 + c0);
    const float* pv = reinterpret_cast<const float*>(&v);
    const float* px = reinterpret_cast<const float*>(&xv);
    float res[4];
#pragma unroll
    for (int j = 0; j < 4; j++) {
        int c = c0 + j;
        float m = gsum[b * 128 + c] * icnt;
        float var = gsq[b * 128 + c] * icnt - m * m;
        float rs = rsqrtf(fmaxf(var, 0.f) + 1e-6f);
        float zn = (pv[j] - m) * rs;
        float r2 = zn + px[j];
        res[j] = r2 > 0.f ? r2 : expm1f(r2);
    }
    *reinterpret_cast<float4*>(o2 + (size_t)n * 128 + c0) =
        *reinterpret_cast<float4*>(res);
}

// ---------------------------------------------------------------------------
extern "C" void kernel_launch(void* const* d_in, const int* in_sizes, int n_in,
                              void* d_out, int out_size, void* d_ws, size_t ws_size,
                              hipStream_t stream) {
    const float* x    = (const float*)d_in[0];
    const float* emb  = (const float*)d_in[1];
    const float* W1   = (const float*)d_in[2];
    const float* W2   = (const float*)d_in[3];
    const float* Wt   = (const float*)d_in[4];
    const float* bt   = (const float*)d_in[5];
    const int* bidx   = (const int*)d_in[6];
    const int* nbr    = (const int*)d_in[7];
    float* out        = (float*)d_out;
    const int N = in_sizes[0] / 128;

    char* ws = (char*)d_ws;
    unsigned short* xb  = (unsigned short*)ws;                          // N*128 bf16 (reused as y)
    unsigned short* o1b = (unsigned short*)(ws + (size_t)N * 256);      // N*128 bf16
    unsigned short* w1p = (unsigned short*)(ws + (size_t)N * 512);      // 27*16384 bf16
    unsigned short* w2p = w1p + 27 * 16384;
    float* e    = (float*)(w2p + 27 * 16384);                           // 8*256
    float* st   = e + 2048;
    float* sum1 = st;
    float* sq1  = st + 1024;
    float* cnt1 = st + 2048;
    float* sum2 = st + 2056;
    float* sq2  = st + 3080;
    float* cnt2 = st + 4104;

    hipMemsetAsync(st, 0, 4112 * sizeof(float), stream);

    int total = N * 128;
    prep_x_kernel<<<(total / 4 + 255) / 256, 256, 0, stream>>>(x, xb, total);
    prep_w_kernel<<<27 * 64, 256, 0, stream>>>(W1, w1p);
    prep_w_kernel<<<27 * 64, 256, 0, stream>>>(W2, w2p);
    film_kernel<<<512, 256, 0, stream>>>(emb, Wt, bt, e);

    conv_kernel<unsigned short><<<N / 128, 256, 0, stream>>>(xb, nbr, w1p, o1b, bidx, sum1, sq1, cnt1, N);
    apply1_kernel<<<(N * 32 + 255) / 256, 256, 0, stream>>>(o1b, bidx, sum1, sq1, cnt1, e, xb, N);

    conv_kernel<float><<<N / 128, 256, 0, stream>>>(xb, nbr, w2p, out, bidx, sum2, sq2, cnt2, N);
    apply2_kernel<<<(N * 32 + 255) / 256, 256, 0, stream>>>(out, x, bidx, sum2, sq2, cnt2, N);
}

// Round 12
// 438.445 us; speedup vs baseline: 1.4596x; 1.0109x over previous
//
#include <hip/hip_runtime.h>
#include <hip/hip_bf16.h>

typedef __bf16 bf16x8 __attribute__((ext_vector_type(8)));
typedef float  f32x4  __attribute__((ext_vector_type(4)));

#define GAS __attribute__((address_space(1)))
#define LAS __attribute__((address_space(3)))

__device__ __forceinline__ unsigned short f2bf(float f) {
    __hip_bfloat16 h = __float2bfloat16(f);
    return *reinterpret_cast<unsigned short*>(&h);
}
__device__ __forceinline__ float bf2f(unsigned short u) {
    __hip_bfloat16 h;
    *reinterpret_cast<unsigned short*>(&h) = u;
    return __bfloat162float(h);
}
__device__ __forceinline__ void storeval(float* p, float v) { *p = v; }
__device__ __forceinline__ void storeval(unsigned short* p, float v) { *p = f2bf(v); }

// ---------------------------------------------------------------------------
// prep: f32 -> bf16 bulk convert (vectorized)
// ---------------------------------------------------------------------------
__global__ void prep_x_kernel(const float* __restrict__ in, unsigned short* __restrict__ out, int total) {
    int idx = (blockIdx.x * 256 + threadIdx.x) * 4;
    if (idx >= total) return;
    float4 v = *reinterpret_cast<const float4*>(in + idx);
    ushort4 o;
    o.x = f2bf(v.x); o.y = f2bf(v.y); o.z = f2bf(v.z); o.w = f2bf(v.w);
    *reinterpret_cast<ushort4*>(out + idx) = o;
}

// ---------------------------------------------------------------------------
// prep: W[k][ci][co] f32 -> Wp[k][h][co][c8*8+j] bf16 (BK=64 halves,
// XOR-swizzled at 16B-chunk granularity — round-3-verified layout)
// ---------------------------------------------------------------------------
__global__ void prep_w_kernel(const float* __restrict__ W, unsigned short* __restrict__ Wp) {
    int idx = blockIdx.x * 256 + threadIdx.x;   // < 27*16384
    int k  = idx >> 14;
    int r  = idx & 16383;
    int h  = r >> 13;
    int rr = r & 8191;
    int co = rr >> 6;
    int cc = rr & 63;
    int c8 = cc >> 3, j = cc & 7;
    int ci = (h << 6) | ((c8 ^ (co & 7)) << 3) | j;
    Wp[idx] = f2bf(W[(k << 14) + ci * 128 + co]);
}

// ---------------------------------------------------------------------------
// FiLM: e[b][j] = emb[b] . Wt[:,j] + bt[j]. One wave per output element.
// ---------------------------------------------------------------------------
__global__ void film_kernel(const float* __restrict__ emb, const float* __restrict__ Wt,
                            const float* __restrict__ bt, float* __restrict__ e) {
    int gw = blockIdx.x * 4 + (threadIdx.x >> 6);   // 0..2047
    int lane = threadIdx.x & 63;
    int b = gw >> 8, j = gw & 255;
    float a = 0.f;
    for (int i = lane; i < 512; i += 64) a += emb[b * 512 + i] * Wt[i * 256 + j];
#pragma unroll
    for (int off = 32; off; off >>= 1) a += __shfl_xor(a, off);
    if (lane == 0) e[gw] = a + bt[j];
}

// ---------------------------------------------------------------------------
// Gather-GEMM sparse conv, h-major order + COUNTED-VMCNT 2-phase pipeline
// (T3/T4 minimum template). All staging via global_load_lds intrinsics only
// (side-effecting -> issue order preserved; the vmcnt count is sound by
// construction — r9's bug was plain-C++ loads breaking the count).
//   prologue: stage(0)                      [8 ops in flight]
//   step s:   stage(s+1) [16 in flight] -> vmcnt(8) drains exactly stage(s)
//             -> s_barrier -> compute(s) -> s_barrier
//   stage(s+1) stays in flight across compute+barriers (~450 cyc cover).
//   tail: vmcnt(0) -> s_barrier -> compute(53).
// sched_barrier(0) fences stop ds_read/MFMA hoisting past the manual waits.
// ---------------------------------------------------------------------------
template <typename OUT_T>
__global__ __launch_bounds__(256, 2) void conv_kernel(
        const unsigned short* __restrict__ X,    // [N][128] bf16
        const int* __restrict__ nbr,             // [N][27]
        const unsigned short* __restrict__ Wp,   // [27][2][128][64] bf16 pre-swizzled
        OUT_T* __restrict__ out,
        const int* __restrict__ bidx,
        float* __restrict__ gsum, float* __restrict__ gsq, float* __restrict__ gcnt,
        int N) {
    __shared__ __align__(16) unsigned short As[2][128 * 64];
    __shared__ __align__(16) unsigned short Bs[2][128 * 64];
    __shared__ int nbrS[128 * 27];
    __shared__ float ssum[2][128];
    __shared__ float ssq[2][128];
    __shared__ float shi;   // count of rows with b == b_hi (when split block)

    const int t = threadIdx.x;
    const int lane = t & 63;
    const int wave = t >> 6;
    const int n0 = blockIdx.x * 128;

    for (int i = t; i < 128 * 27; i += 256) nbrS[i] = nbr[(size_t)n0 * 27 + i];
    if (t < 128) { ssum[0][t] = 0.f; ssum[1][t] = 0.f; ssq[0][t] = 0.f; ssq[1][t] = 0.f; }
    if (t == 0) shi = 0.f;

    f32x4 acc[4][4];
#pragma unroll
    for (int mi = 0; mi < 4; mi++)
#pragma unroll
        for (int ni = 0; ni < 4; ni++) acc[mi][ni] = (f32x4){0.f, 0.f, 0.f, 0.f};

    const int wr = wave >> 1, wc = wave & 1;
    const int l15 = lane & 15, l4 = lane >> 4;

    // h-major: sidx 0..26 -> (h=0, k=sidx); 27..53 -> (h=1, k=sidx-27)
    auto stage = [&](int sidx) {
        const int h1 = sidx >= 27 ? 1 : 0;
        const int k1 = sidx - h1 * 27;
        unsigned short* Ad = &As[sidx & 1][0];
        unsigned short* Bd = &Bs[sidx & 1][0];
#pragma unroll
        for (int i = 0; i < 4; ++i) {
            int chunk = i * 256 + t;
            int row = chunk >> 3;
            int c8 = chunk & 7;
            int g = c8 ^ (row & 7);               // inverse-swizzled source chunk
            int srow = nbrS[row * 27 + k1];
            __builtin_amdgcn_global_load_lds(
                (const GAS void*)(X + (size_t)srow * 128 + h1 * 64 + g * 8),
                (LAS void*)(Ad + (size_t)(i * 256 + wave * 64) * 8), 16, 0, 0);
        }
        const unsigned short* wsrc = Wp + (size_t)(k1 * 2 + h1) * 8192;
#pragma unroll
        for (int i = 0; i < 4; ++i) {
            __builtin_amdgcn_global_load_lds(
                (const GAS void*)(wsrc + (size_t)(i * 256 + t) * 8),
                (LAS void*)(Bd + (size_t)(i * 256 + wave * 64) * 8), 16, 0, 0);
        }
    };
    auto computeStep = [&](int buf) {
#pragma unroll
        for (int kk = 0; kk < 2; ++kk) {
            const int c8 = kk * 4 + l4;
            bf16x8 a[4], b[4];
#pragma unroll
            for (int mi = 0; mi < 4; mi++) {
                int row = wr * 64 + mi * 16 + l15;
                a[mi] = *reinterpret_cast<const bf16x8*>(&As[buf][row * 64 + (c8 ^ (row & 7)) * 8]);
            }
#pragma unroll
            for (int ni = 0; ni < 4; ni++) {
                int co = wc * 64 + ni * 16 + l15;
                b[ni] = *reinterpret_cast<const bf16x8*>(&Bs[buf][co * 64 + (c8 ^ (co & 7)) * 8]);
            }
#pragma unroll
            for (int mi = 0; mi < 4; mi++)
#pragma unroll
                for (int ni = 0; ni < 4; ni++)
                    acc[mi][ni] = __builtin_amdgcn_mfma_f32_16x16x32_bf16(a[mi], b[ni], acc[mi][ni], 0, 0, 0);
        }
    };

    __syncthreads();           // nbrS + stats LDS ready
    stage(0);                  // 8 ops in flight, NOT drained

    for (int s = 0; s < 53; ++s) {
        stage(s + 1);          // 16 in flight
        __builtin_amdgcn_sched_barrier(0);
        asm volatile("s_waitcnt vmcnt(8)" ::: "memory");   // drains stage(s)
        __builtin_amdgcn_sched_barrier(0);
        __builtin_amdgcn_s_barrier();       // buf[s&1] complete for all waves
        __builtin_amdgcn_sched_barrier(0);
        computeStep(s & 1);
        __builtin_amdgcn_sched_barrier(0);
        __builtin_amdgcn_s_barrier();       // buf[s&1] consumed by all waves
        __builtin_amdgcn_sched_barrier(0);
    }
    // tail: s = 53
    asm volatile("s_waitcnt vmcnt(0)" ::: "memory");
    __builtin_amdgcn_sched_barrier(0);
    __builtin_amdgcn_s_barrier();
    __builtin_amdgcn_sched_barrier(0);
    computeStep(1);

    // ---- epilogue: store + fused instance-norm stats ----
    const int b_lo = bidx[n0];
    const int b_hi = bidx[n0 + 127];
    const bool split = (b_hi != b_lo);

    float ps0[4] = {0.f, 0.f, 0.f, 0.f}, ps1[4] = {0.f, 0.f, 0.f, 0.f};
    float pq0[4] = {0.f, 0.f, 0.f, 0.f}, pq1[4] = {0.f, 0.f, 0.f, 0.f};
#pragma unroll
    for (int mi = 0; mi < 4; mi++) {
#pragma unroll
        for (int j = 0; j < 4; j++) {
            int rowm = wr * 64 + mi * 16 + l4 * 4 + j;
            bool hi = split && (bidx[n0 + rowm] != b_lo);
#pragma unroll
            for (int ni = 0; ni < 4; ni++) {
                float v = acc[mi][ni][j];
                float v1 = hi ? v : 0.f;
                float v0 = v - v1;
                ps0[ni] += v0; pq0[ni] += v0 * v;
                ps1[ni] += v1; pq1[ni] += v1 * v;
                int col = wc * 64 + ni * 16 + l15;
                storeval(out + (size_t)(n0 + rowm) * 128 + col, v);
            }
        }
    }
#pragma unroll
    for (int ni = 0; ni < 4; ni++) {
        int col = wc * 64 + ni * 16 + l15;
        atomicAdd(&ssum[0][col], ps0[ni]);
        atomicAdd(&ssq[0][col], pq0[ni]);
        if (split) {
            atomicAdd(&ssum[1][col], ps1[ni]);
            atomicAdd(&ssq[1][col], pq1[ni]);
        }
    }
    if (split && wave < 2) {
        bool hi = (bidx[n0 + t] != b_lo);
        unsigned long long m = __ballot(hi);
        if (lane == 0) atomicAdd(&shi, (float)__popcll(m));
    }
    __syncthreads();
    {
        int slot = t >> 7, c = t & 127;
        if (slot == 0 || split) {
            int b = slot ? b_hi : b_lo;
            atomicAdd(&gsum[b * 128 + c], ssum[slot][c]);
            atomicAdd(&gsq[b * 128 + c], ssq[slot][c]);
        }
        if (t == 0) {
            float nhi = shi;
            atomicAdd(&gcnt[b_lo], 128.f - nhi);
            if (split) atomicAdd(&gcnt[b_hi], nhi);
        }
    }
}

// ---------------------------------------------------------------------------
// apply1: y = elu( norm(out1) * (1+scale) + shift )  -> bf16
// ---------------------------------------------------------------------------
__global__ void apply1_kernel(const unsigned short* __restrict__ o1, const int* __restrict__ bidx,
                              const float* __restrict__ gsum, const float* __restrict__ gsq,
                              const float* __restrict__ gcnt, const float* __restrict__ e,
                              unsigned short* __restrict__ y, int N) {
    int idx = blockIdx.x * 256 + threadIdx.x;
    int n = idx >> 5;
    if (n >= N) return;
    int c0 = (idx & 31) << 2;
    int b = bidx[n];
    float icnt = 1.0f / fmaxf(gcnt[b], 1.0f);
    ushort4 vv = *reinterpret_cast<const ushort4*>(o1 + (size_t)n * 128 + c0);
    const unsigned short* pv = reinterpret_cast<const unsigned short*>(&vv);
    unsigned short res[4];
#pragma unroll
    for (int j = 0; j < 4; j++) {
        int c = c0 + j;
        float m = gsum[b * 128 + c] * icnt;
        float var = gsq[b * 128 + c] * icnt - m * m;
        float rs = rsqrtf(fmaxf(var, 0.f) + 1e-6f);
        float xn = (bf2f(pv[j]) - m) * rs;
        float sc = e[b * 256 + c];
        float sh = e[b * 256 + 128 + c];
        float tt = xn * (1.0f + sc) + sh;
        float r = tt > 0.f ? tt : expm1f(tt);
        res[j] = f2bf(r);
    }
    *reinterpret_cast<ushort4*>(y + (size_t)n * 128 + c0) = *reinterpret_cast<ushort4*>(res);
}

// ---------------------------------------------------------------------------
// apply2: out = elu( norm(out2) + x_feats )  -> f32, in place on d_out
// ---------------------------------------------------------------------------
__global__ void apply2_kernel(float* __restrict__ o2, const float* __restrict__ xf,
                              const int* __restrict__ bidx, const float* __restrict__ gsum,
                              const float* __restrict__ gsq, const float* __restrict__ gcnt, int N) {
    int idx = blockIdx.x * 256 + threadIdx.x;
    int n = idx >> 5;
    if (n >= N) return;
    int c0 = (idx & 31) << 2;
    int b = bidx[n];
    float icnt = 1.0f / fmaxf(gcnt[b], 1.0f);
    float4 v = *reinterpret_cast<const float4*>(o2 + (size_t)n * 128 + c0);
    float4 xv = *reinterpret_cast<const float4*>(xf + (size_t)n * 128 + c0);
    const float* pv = reinterpret_cast<const float*>(&v);
    const float* px = reinterpret_cast<const float*>(&xv);
    float res[4];
#pragma unroll
    for (int j = 0; j < 4; j++) {
        int c = c0 + j;
        float m = gsum[b * 128 + c] * icnt;
        float var = gsq[b * 128 + c] * icnt - m * m;
        float rs = rsqrtf(fmaxf(var, 0.f) + 1e-6f);
        float zn = (pv[j] - m) * rs;
        float r2 = zn + px[j];
        res[j] = r2 > 0.f ? r2 : expm1f(r2);
    }
    *reinterpret_cast<float4*>(o2 + (size_t)n * 128 + c0) =
        *reinterpret_cast<float4*>(res);
}

// ---------------------------------------------------------------------------
extern "C" void kernel_launch(void* const* d_in, const int* in_sizes, int n_in,
                              void* d_out, int out_size, void* d_ws, size_t ws_size,
                              hipStream_t stream) {
    const float* x    = (const float*)d_in[0];
    const float* emb  = (const float*)d_in[1];
    const float* W1   = (const float*)d_in[2];
    const float* W2   = (const float*)d_in[3];
    const float* Wt   = (const float*)d_in[4];
    const float* bt   = (const float*)d_in[5];
    const int* bidx   = (const int*)d_in[6];
    const int* nbr    = (const int*)d_in[7];
    float* out        = (float*)d_out;
    const int N = in_sizes[0] / 128;

    char* ws = (char*)d_ws;
    unsigned short* xb  = (unsigned short*)ws;                          // N*128 bf16 (reused as y)
    unsigned short* o1b = (unsigned short*)(ws + (size_t)N * 256);      // N*128 bf16
    unsigned short* w1p = (unsigned short*)(ws + (size_t)N * 512);      // 27*16384 bf16
    unsigned short* w2p = w1p + 27 * 16384;
    float* e    = (float*)(w2p + 27 * 16384);                           // 8*256
    float* st   = e + 2048;
    float* sum1 = st;
    float* sq1  = st + 1024;
    float* cnt1 = st + 2048;
    float* sum2 = st + 2056;
    float* sq2  = st + 3080;
    float* cnt2 = st + 4104;

    hipMemsetAsync(st, 0, 4112 * sizeof(float), stream);

    int total = N * 128;
    prep_x_kernel<<<(total / 4 + 255) / 256, 256, 0, stream>>>(x, xb, total);
    prep_w_kernel<<<27 * 64, 256, 0, stream>>>(W1, w1p);
    prep_w_kernel<<<27 * 64, 256, 0, stream>>>(W2, w2p);
    film_kernel<<<512, 256, 0, stream>>>(emb, Wt, bt, e);

    conv_kernel<unsigned short><<<N / 128, 256, 0, stream>>>(xb, nbr, w1p, o1b, bidx, sum1, sq1, cnt1, N);
    apply1_kernel<<<(N * 32 + 255) / 256, 256, 0, stream>>>(o1b, bidx, sum1, sq1, cnt1, e, xb, N);

    conv_kernel<float><<<N / 128, 256, 0, stream>>>(xb, nbr, w2p, out, bidx, sum2, sq2, cnt2, N);
    apply2_kernel<<<(N * 32 + 255) / 256, 256, 0, stream>>>(out, x, bidx, sum2, sq2, cnt2, N);
}